// Round 10
// baseline (344.313 us; speedup 1.0000x reference)
//
#include <hip/hip_runtime.h>
#include <hip/hip_fp16.h>

#define F_IN 128
#define C_DIM 300
#define NEG_SLOPE 0.2f
#define NCT  40           // col-tile count for Bp (640 padded cols)
#define CH   8            // edges per chunk in gat_gather
#define NCONV 320         // convert_w blocks in prep

typedef _Float16 half8 __attribute__((ext_vector_type(8)));
typedef _Float16 half4 __attribute__((ext_vector_type(4)));
typedef _Float16 h2    __attribute__((ext_vector_type(2)));
typedef float    f32x4 __attribute__((ext_vector_type(4)));
typedef float    f32x2 __attribute__((ext_vector_type(2)));

__device__ inline h2 as_h2(unsigned u) { union { unsigned u; h2 h; } c; c.u = u; return c.h; }
__device__ inline unsigned as_u(h2 h)  { union { unsigned u; h2 h; } c; c.h = h; return c.u; }
__device__ inline f32x2 upv(unsigned u) {
    h2 h = as_h2(u);
    f32x2 r; r.x = (float)h.x; r.y = (float)h.y; return r;
}
__device__ inline f32x2 fma2(f32x2 a, f32x2 b, f32x2 c) {
#if __has_builtin(__builtin_elementwise_fma)
    return __builtin_elementwise_fma(a, b, c);
#else
    f32x2 r; r.x = fmaf(a.x, b.x, c.x); r.y = fmaf(a.y, b.y, c.y); return r;
#endif
}

#if __has_builtin(__builtin_amdgcn_fdot2)
__device__ inline float fdot2w(h2 a, h2 b, float c) {
    return __builtin_amdgcn_fdot2(a, b, c, false);
}
#else
__device__ inline float fdot2w(h2 a, h2 b, float c) {
    return fmaf((float)a.y, (float)b.y, fmaf((float)a.x, (float)b.x, c));
}
#endif

// ---------- prep: convert_w (blocks [0,NCONV)) + hist (rest); no LDS ----------
__global__ __launch_bounds__(256) void prep(
    const float* __restrict__ Wl, const float* __restrict__ Wr,
    _Float16* __restrict__ Bp, const int* __restrict__ dst,
    unsigned* __restrict__ counts, int nE)
{
    if ((int)blockIdx.x < NCONV) {
        int idx = blockIdx.x * 256 + threadIdx.x;        // 0 .. 640*128-1
        if (idx >= 640 * F_IN) return;
        int nn = idx % 640;                               // coalesced W reads
        int k  = idx / 640;
        float v = 0.f;
        if (nn < 300)                   v = Wl[k * C_DIM + nn];
        else if (nn >= 304 && nn < 604) v = Wr[k * C_DIM + (nn - 304)];
        int ct = nn >> 4, n16 = nn & 15;
        int kr = k & 31,  ks  = k >> 5;
        int lane = ((kr >> 3) << 4) | n16;
        int j = k & 7;
        Bp[((((ct * 4 + ks) * 64) + lane) << 3) | j] = (_Float16)v;
    } else {
        int j = (blockIdx.x - NCONV) * 256 + threadIdx.x;
        if (j < nE) atomicAdd(counts + dst[j], 1u);
    }
}

// ---------- scan_all: single-block exclusive scan, wave-shuffle based ----------
// 1024 threads, tiles of 4096; writes offs[0..n] and cursor[0..n)
__global__ __launch_bounds__(1024) void scan_all(
    const unsigned* __restrict__ counts, unsigned* __restrict__ offs,
    unsigned* __restrict__ cursor, int n)
{
    __shared__ unsigned wsum[16];
    __shared__ unsigned wbase[16];
    __shared__ unsigned stot;
    const int t = threadIdx.x;
    const int lane = t & 63;
    const int wv = t >> 6;
    unsigned base = 0;
    const int ntiles = (n + 4095) >> 12;
    for (int tile = 0; tile < ntiles; ++tile) {
        const int i0 = tile * 4096 + t * 4;
        uint4 c = make_uint4(0, 0, 0, 0);
        if (i0 + 3 < n) {
            c = *reinterpret_cast<const uint4*>(counts + i0);
        } else if (i0 < n) {
            c.x = counts[i0];
            if (i0 + 1 < n) c.y = counts[i0 + 1];
            if (i0 + 2 < n) c.z = counts[i0 + 2];
        }
        unsigned v = c.x + c.y + c.z + c.w;
        unsigned inc = v;
        #pragma unroll
        for (int off = 1; off < 64; off <<= 1) {
            unsigned u = __shfl_up(inc, off);
            if (lane >= off) inc += u;
        }
        if (lane == 63) wsum[wv] = inc;
        __syncthreads();
        if (t < 16) {
            unsigned wvv = wsum[t];
            unsigned winc = wvv;
            #pragma unroll
            for (int off = 1; off < 16; off <<= 1) {
                unsigned u = __shfl_up(winc, off);
                if (t >= off) winc += u;
            }
            wbase[t] = winc - wvv;
            if (t == 15) stot = winc;
        }
        __syncthreads();
        unsigned run = base + wbase[wv] + (inc - v);
        if (i0 < n) {
            unsigned o0 = run;
            unsigned o1 = o0 + c.x;
            unsigned o2 = o1 + c.y;
            unsigned o3 = o2 + c.z;
            if (i0 + 3 < n) {
                uint4 o = make_uint4(o0, o1, o2, o3);
                *reinterpret_cast<uint4*>(offs + i0) = o;
                *reinterpret_cast<uint4*>(cursor + i0) = o;
            } else {
                offs[i0] = o0; cursor[i0] = o0;
                if (i0 + 1 < n) { offs[i0 + 1] = o1; cursor[i0 + 1] = o1; }
                if (i0 + 2 < n) { offs[i0 + 2] = o2; cursor[i0 + 2] = o2; }
            }
        }
        base += stot;
        __syncthreads();          // protect wsum/stot before next tile
    }
    if (t == 0) offs[n] = base;
}

// ---------- scatter_csr: standalone, zero LDS, full occupancy ----------
__global__ __launch_bounds__(256) void scatter_csr(
    const int* __restrict__ src, const int* __restrict__ dst,
    unsigned* __restrict__ cursor, int* __restrict__ csr_src, int nE)
{
    int j = blockIdx.x * blockDim.x + threadIdx.x;
    if (j < nE) {
        unsigned p = atomicAdd(cursor + dst[j], 1u);
        csr_src[p] = src[j];
    }
}

// ---------- gemm: LDS-free; 128 rows/block, wave owns 2x16-row tiles ----------
// A loaded directly from global (fp32 -> f16 in regs); B from pre-swizzled Bp.
__global__ __launch_bounds__(256) void gemm_xlxr(
    const float* __restrict__ x, const _Float16* __restrict__ Bp,
    const float* __restrict__ bl, const float* __restrict__ br,
    _Float16* __restrict__ xlh, _Float16* __restrict__ xrh, int n)
{
    const int t    = threadIdx.x;
    const int w    = t >> 6;
    const int lane = t & 63;
    const int m    = lane & 15;
    const int quad = lane >> 4;

    const int tb0 = blockIdx.x * 128 + w * 32;       // wave's 32-row strip
    const int ra0 = min(tb0 + m, n - 1);             // A row, tile 0 (clamped)
    const int ra1 = min(tb0 + 16 + m, n - 1);        // A row, tile 1

    half8 a0[4], a1[4];
    #pragma unroll
    for (int ks = 0; ks < 4; ++ks) {
        const float* p0 = x + (size_t)ra0 * F_IN + ks * 32 + quad * 8;
        const float* p1 = x + (size_t)ra1 * F_IN + ks * 32 + quad * 8;
        float4 u0 = *reinterpret_cast<const float4*>(p0);
        float4 u1 = *reinterpret_cast<const float4*>(p0 + 4);
        float4 v0 = *reinterpret_cast<const float4*>(p1);
        float4 v1 = *reinterpret_cast<const float4*>(p1 + 4);
        a0[ks] = (half8){(_Float16)u0.x, (_Float16)u0.y, (_Float16)u0.z, (_Float16)u0.w,
                         (_Float16)u1.x, (_Float16)u1.y, (_Float16)u1.z, (_Float16)u1.w};
        a1[ks] = (half8){(_Float16)v0.x, (_Float16)v0.y, (_Float16)v0.z, (_Float16)v0.w,
                         (_Float16)v1.x, (_Float16)v1.y, (_Float16)v1.z, (_Float16)v1.w};
    }

    const int rb = tb0 + quad * 4;                   // C row base, tile 0

    #pragma unroll 2
    for (int ct = 0; ct < NCT; ++ct) {
        f32x4 acc0 = {0.f, 0.f, 0.f, 0.f};
        f32x4 acc1 = {0.f, 0.f, 0.f, 0.f};
        #pragma unroll
        for (int ks = 0; ks < 4; ++ks) {
            half8 b = *reinterpret_cast<const half8*>(
                Bp + (((size_t)(ct * 4 + ks) * 64 + lane) << 3));
            acc0 = __builtin_amdgcn_mfma_f32_16x16x32_f16(a0[ks], b, acc0, 0, 0, 0);
            acc1 = __builtin_amdgcn_mfma_f32_16x16x32_f16(a1[ks], b, acc1, 0, 0, 0);
        }
        int col = ct * 16 + m;
        int isL = (col < 300);
        int isR = (col >= 304 && col < 604);
        if (isL | isR) {
            float bv = isL ? bl[col] : br[col - 304];
            _Float16* tab = isL ? (xlh + col) : (xrh + (col - 304));
            #pragma unroll
            for (int reg = 0; reg < 4; ++reg) {
                int r0 = rb + reg;
                int r1 = r0 + 16;
                if (r0 < n) tab[(size_t)r0 * C_DIM] = (_Float16)(acc0[reg] + bv);
                if (r1 < n) tab[(size_t)r1 * C_DIM] = (_Float16)(acc1[reg] + bv);
            }
        }
    }
}

// ---------- gat_gather: fused per-node gather, chunked softmax (8 edges/iter) ----------
__global__ __launch_bounds__(256) void gat_gather(
    const int* __restrict__ csr_src, const unsigned* __restrict__ offs,
    const _Float16* __restrict__ xlh, const _Float16* __restrict__ xrh,
    const float* __restrict__ att, const float* __restrict__ bias,
    const float* __restrict__ lw, const float* __restrict__ lb,
    float* __restrict__ y, int n)
{
    __shared__ __align__(16) float lds[4 * 560];   // per wave: part[8][68]
    float* part = lds + (threadIdx.x >> 6) * 560;

    const int wid  = (blockIdx.x * blockDim.x + threadIdx.x) >> 6;
    const int lane = threadIdx.x & 63;
    if (wid >= n) return;

    const int l2   = 2 * lane;
    const bool has2 = (lane < 22);
    const int t8   = lane & 7;
    const int o    = lane >> 3;
    const int byteoff = lane * 4;

    const _Float16* xrrow = xrh + (size_t)wid * C_DIM;
    h2 xr0 = *(const h2*)(xrrow + l2);
    h2 xr1 = *(const h2*)(xrrow + 128 + l2);
    h2 xr2 = {(_Float16)0, (_Float16)0};
    if (has2) xr2 = *(const h2*)(xrrow + 256 + l2);

    h2 a06[3], a04[3];
    #pragma unroll
    for (int k = 0; k < 3; ++k) {
        int c = 128 * k + l2;
        float ax = (c < C_DIM) ? att[c] : 0.f;
        float ay = (c + 1 < C_DIM) ? att[c + 1] : 0.f;
        a06[k].x = (_Float16)(0.6f * ax); a06[k].y = (_Float16)(0.6f * ay);
        a04[k].x = (_Float16)(0.4f * ax); a04[k].y = (_Float16)(0.4f * ay);
    }

    f32x2 acc2[3] = {{0.f, 0.f}, {0.f, 0.f}, {0.f, 0.f}};
    float den = 0.f;

    const unsigned start = offs[wid];
    const int totalE = (int)(offs[wid + 1] - start) + 1;   // + self loop (k==0)
    const char* basep = (const char*)xlh;

    for (int base = 0; base < totalE; base += CH) {
        int idv = wid;                                      // self-loop & filler
        {
            int k = base + lane;
            if (lane < CH && k > 0 && k < totalE) idv = csr_src[start + k - 1];
        }
        int rowb = idv * (C_DIM * 2);
        int ro[CH];
        #pragma unroll
        for (int tt = 0; tt < CH; ++tt) ro[tt] = __shfl(rowb, tt);

        unsigned pk0[CH], pk1[CH], pk2[CH];
        #pragma unroll
        for (int tt = 0; tt < CH; ++tt) {
            const char* p = basep + ro[tt] + byteoff;
            pk0[tt] = *(const unsigned*)(p);
            pk1[tt] = *(const unsigned*)(p + 256);
            pk2[tt] = 0u;
        }
        if (has2) {
            #pragma unroll
            for (int tt = 0; tt < CH; ++tt)
                pk2[tt] = *(const unsigned*)(basep + ro[tt] + byteoff + 512);
        }

        #pragma unroll
        for (int tt = 0; tt < CH; ++tt) {
            h2 z0 = as_h2(pk0[tt]) + xr0;
            h2 z1 = as_h2(pk1[tt]) + xr1;
            h2 z2 = as_h2(pk2[tt]) + xr2;
            float p = fdot2w(z0, a06[0], 0.f);
            p = fdot2w(as_h2(as_u(z0) & 0x7FFF7FFFu), a04[0], p);
            p = fdot2w(z1, a06[1], p);
            p = fdot2w(as_h2(as_u(z1) & 0x7FFF7FFFu), a04[1], p);
            p = fdot2w(z2, a06[2], p);
            p = fdot2w(as_h2(as_u(z2) & 0x7FFF7FFFu), a04[2], p);
            part[tt * 68 + lane] = p;
        }

        float wgt;
        {
            const int oo = (o + t8) & 7;
            const float* rp = part + t8 * 68 + oo * 8;
            float4 s0 = *(const float4*)(rp + 0);
            float4 s1 = *(const float4*)(rp + 4);
            float e = ((s0.x + s0.y) + (s0.z + s0.w)) + ((s1.x + s1.y) + (s1.z + s1.w));
            e += __shfl_xor(e, 8);
            e += __shfl_xor(e, 16);
            e += __shfl_xor(e, 32);
            bool valid = (base + t8) < totalE;
            wgt = valid ? __expf(fminf(e, 60.f)) : 0.f;
        }

        #pragma unroll
        for (int tt = 0; tt < CH; ++tt) {
            float wt = __shfl(wgt, tt);
            den += wt;
            f32x2 wt2 = {wt, wt};
            acc2[0] = fma2(wt2, upv(pk0[tt]), acc2[0]);
            acc2[1] = fma2(wt2, upv(pk1[tt]), acc2[1]);
            acc2[2] = fma2(wt2, upv(pk2[tt]), acc2[2]);
        }
    }

    const float invd = 1.f / den;
    float dot = 0.f;
    #pragma unroll
    for (int k = 0; k < 3; ++k) {
        #pragma unroll
        for (int j = 0; j < 2; ++j) {
            int c = 128 * k + l2 + j;
            float b = (c < C_DIM) ? bias[c] : 0.f;
            float l = (c < C_DIM) ? lw[c] : 0.f;
            float a = (j == 0) ? acc2[k].x : acc2[k].y;
            float h = fmaf(a, invd, b);
            h = h > 0.f ? h : 0.f;
            dot = fmaf(h, l, dot);
        }
    }
    #pragma unroll
    for (int off = 32; off; off >>= 1) dot += __shfl_xor(dot, off);
    if (lane == 0) y[wid] = 1.f / (1.f + __expf(-(dot + lb[0])));
}

extern "C" void kernel_launch(void* const* d_in, const int* in_sizes, int n_in,
                              void* d_out, int out_size, void* d_ws, size_t ws_size,
                              hipStream_t stream)
{
    const float* x    = (const float*)d_in[0];
    const int*   ei   = (const int*)d_in[1];
    const float* Wl   = (const float*)d_in[2];
    const float* bl   = (const float*)d_in[3];
    const float* Wr   = (const float*)d_in[4];
    const float* br   = (const float*)d_in[5];
    const float* att  = (const float*)d_in[6];
    const float* bias = (const float*)d_in[7];
    const float* lw   = (const float*)d_in[8];
    const float* lb   = (const float*)d_in[9];
    float* y = (float*)d_out;

    const int n  = in_sizes[0] / F_IN;   // 50000
    const int nE = in_sizes[1] / 2;      // 800000
    const int* src_arr = ei;
    const int* dst_arr = ei + nE;
    const int nhist = (nE + 255) / 256;    // 3125
    const int ngemm = (n + 127) / 128;     // 391

    // ws: xlh | xrh | Bp | counts | offs(n+1 pad to n+4) | cursor | csr_src
    _Float16* xlh     = (_Float16*)d_ws;
    _Float16* xrh     = xlh + (size_t)n * C_DIM;
    _Float16* Bp      = xrh + (size_t)n * C_DIM;
    unsigned* counts  = (unsigned*)(Bp + NCT * 4 * 64 * 8);
    unsigned* offs    = counts + n;
    unsigned* cursor  = offs + ((n + 4) & ~3);     // keep 16B alignment
    int*      csr_src = (int*)(cursor + ((n + 4) & ~3));

    hipMemsetAsync(counts, 0, (size_t)n * sizeof(unsigned), stream);
    prep<<<NCONV + nhist, 256, 0, stream>>>(Wl, Wr, Bp, dst_arr, counts, nE);
    scan_all<<<1, 1024, 0, stream>>>(counts, offs, cursor, n);
    scatter_csr<<<nhist, 256, 0, stream>>>(src_arr, dst_arr, cursor, csr_src, nE);
    gemm_xlxr<<<ngemm, 256, 0, stream>>>(x, Bp, bl, br, xlh, xrh, n);
    gat_gather<<<(n + 3) / 4, 256, 0, stream>>>(csr_src, offs, xlh, xrh, att, bias, lw, lb, y, n);
}

// Round 11
// 320.605 us; speedup vs baseline: 1.0739x; 1.0739x over previous
//
#include <hip/hip_runtime.h>
#include <hip/hip_fp16.h>

#define F_IN 128
#define C_DIM 300
#define NEG_SLOPE 0.2f
#define NCT  40           // col-tile count for Bp (640 padded cols)
#define CH   8            // edges per chunk in gat_gather

typedef _Float16 half8 __attribute__((ext_vector_type(8)));
typedef _Float16 half4 __attribute__((ext_vector_type(4)));
typedef _Float16 h2    __attribute__((ext_vector_type(2)));
typedef float    f32x4 __attribute__((ext_vector_type(4)));
typedef float    f32x2 __attribute__((ext_vector_type(2)));

__device__ inline h2 as_h2(unsigned u) { union { unsigned u; h2 h; } c; c.u = u; return c.h; }
__device__ inline unsigned as_u(h2 h)  { union { unsigned u; h2 h; } c; c.h = h; return c.u; }
__device__ inline f32x2 upv(unsigned u) {
    h2 h = as_h2(u);
    f32x2 r; r.x = (float)h.x; r.y = (float)h.y; return r;
}
__device__ inline f32x2 fma2(f32x2 a, f32x2 b, f32x2 c) {
#if __has_builtin(__builtin_elementwise_fma)
    return __builtin_elementwise_fma(a, b, c);
#else
    f32x2 r; r.x = fmaf(a.x, b.x, c.x); r.y = fmaf(a.y, b.y, c.y); return r;
#endif
}

#if __has_builtin(__builtin_amdgcn_fdot2)
__device__ inline float fdot2w(h2 a, h2 b, float c) {
    return __builtin_amdgcn_fdot2(a, b, c, false);
}
#else
__device__ inline float fdot2w(h2 a, h2 b, float c) {
    return fmaf((float)a.y, (float)b.y, fmaf((float)a.x, (float)b.x, c));
}
#endif

// ---------- K0: build fragment-ready f16 weight layout (coalesced reads) ----------
__global__ __launch_bounds__(256) void convert_w(
    const float* __restrict__ Wl, const float* __restrict__ Wr,
    _Float16* __restrict__ Bp)
{
    int idx = blockIdx.x * 256 + threadIdx.x;        // 0 .. 640*128-1
    if (idx >= 640 * F_IN) return;
    int nn = idx % 640;                               // fastest -> coalesced W reads
    int k  = idx / 640;
    float v = 0.f;
    if (nn < 300)                   v = Wl[k * C_DIM + nn];
    else if (nn >= 304 && nn < 604) v = Wr[k * C_DIM + (nn - 304)];
    int ct = nn >> 4, n16 = nn & 15;
    int kr = k & 31,  ks  = k >> 5;
    int lane = ((kr >> 3) << 4) | n16;
    int j = k & 7;
    Bp[((((ct * 4 + ks) * 64) + lane) << 3) | j] = (_Float16)v;
}

// ---------- hist ----------
__global__ __launch_bounds__(256) void hist_kernel(
    const int* __restrict__ dst, unsigned* __restrict__ counts, int nE)
{
    int j = blockIdx.x * blockDim.x + threadIdx.x;
    if (j < nE) atomicAdd(counts + dst[j], 1u);
}

// ---- 3-phase multi-block exclusive scan (1024 counts per block) ----
__global__ __launch_bounds__(256) void scan_part(
    const unsigned* __restrict__ counts, unsigned* __restrict__ bsum, int n)
{
    __shared__ unsigned s[256];
    const int t = threadIdx.x;
    const int base = blockIdx.x * 1024 + t * 4;
    unsigned v = 0;
    #pragma unroll
    for (int i = 0; i < 4; ++i) {
        int idx = base + i;
        if (idx < n) v += counts[idx];
    }
    s[t] = v;
    __syncthreads();
    for (int off = 128; off > 0; off >>= 1) {
        if (t < off) s[t] += s[t + off];
        __syncthreads();
    }
    if (t == 0) bsum[blockIdx.x] = s[0];
}

__global__ __launch_bounds__(64) void scan_mid(
    unsigned* __restrict__ bsum, unsigned* __restrict__ offs, int nblk, int n)
{
    const int lane = threadIdx.x;
    unsigned v = (lane < nblk) ? bsum[lane] : 0u;
    unsigned inc = v;
    #pragma unroll
    for (int off = 1; off < 64; off <<= 1) {
        unsigned u = __shfl_up(inc, off);
        if (lane >= off) inc += u;
    }
    if (lane < nblk) bsum[lane] = inc - v;
    if (lane == 63) offs[n] = inc;
}

__global__ __launch_bounds__(256) void scan_final(
    const unsigned* __restrict__ counts, const unsigned* __restrict__ bsum,
    unsigned* __restrict__ offs, unsigned* __restrict__ cursor, int n)
{
    __shared__ unsigned s[256];
    const int t = threadIdx.x;
    const int base = blockIdx.x * 1024 + t * 4;
    unsigned c[4];
    unsigned v = 0;
    #pragma unroll
    for (int i = 0; i < 4; ++i) {
        int idx = base + i;
        c[i] = (idx < n) ? counts[idx] : 0u;
        v += c[i];
    }
    s[t] = v;
    __syncthreads();
    for (int off = 1; off < 256; off <<= 1) {
        unsigned u = (t >= off) ? s[t - off] : 0u;
        __syncthreads();
        if (t >= off) s[t] += u;
        __syncthreads();
    }
    unsigned run = bsum[blockIdx.x] + s[t] - v;
    #pragma unroll
    for (int i = 0; i < 4; ++i) {
        int idx = base + i;
        if (idx < n) {
            offs[idx] = run;
            cursor[idx] = run;
            run += c[i];
        }
    }
}

// ---------- scatter_csr: standalone, zero LDS, full occupancy ----------
__global__ __launch_bounds__(256) void scatter_csr(
    const int* __restrict__ src, const int* __restrict__ dst,
    unsigned* __restrict__ cursor, int* __restrict__ csr_src, int nE)
{
    int j = blockIdx.x * blockDim.x + threadIdx.x;
    if (j < nE) {
        unsigned p = atomicAdd(cursor + dst[j], 1u);
        csr_src[p] = src[j];
    }
}

// ---------- gemm: 64-row blocks (LDS-staged), wave owns 16 rows, sweeps 40 col-tiles ----------
__global__ __launch_bounds__(256) void gemm_xlxr(
    const float* __restrict__ x, const _Float16* __restrict__ Bp,
    const float* __restrict__ bl, const float* __restrict__ br,
    _Float16* __restrict__ xlh, _Float16* __restrict__ xrh, int n)
{
    __shared__ __align__(16) _Float16 xs[64][136];
    const int rb0 = blockIdx.x * 64;
    const int t   = threadIdx.x;

    #pragma unroll
    for (int i = 0; i < 8; ++i) {
        int flat = (i * 256 + t) * 4;
        int r = flat >> 7;
        int k = flat & 127;
        int gr = rb0 + r;
        if (gr >= n) gr = n - 1;
        float4 v = *reinterpret_cast<const float4*>(x + (size_t)gr * F_IN + k);
        half4 h = { (_Float16)v.x, (_Float16)v.y, (_Float16)v.z, (_Float16)v.w };
        *reinterpret_cast<half4*>(&xs[r][k]) = h;
    }
    __syncthreads();

    const int w    = t >> 6;
    const int lane = t & 63;
    const int m    = lane & 15;
    const int quad = lane >> 4;

    // A-fragments for this wave's 16 rows, all 4 K-steps, kept in regs
    half8 a[4];
    #pragma unroll
    for (int ks = 0; ks < 4; ++ks)
        a[ks] = *reinterpret_cast<const half8*>(&xs[w * 16 + m][ks * 32 + quad * 8]);

    const int rbase = rb0 + w * 16 + quad * 4;

    #pragma unroll 4
    for (int ct = 0; ct < NCT; ++ct) {
        f32x4 acc = {0.f, 0.f, 0.f, 0.f};
        #pragma unroll
        for (int ks = 0; ks < 4; ++ks) {
            half8 b = *reinterpret_cast<const half8*>(
                Bp + (((size_t)(ct * 4 + ks) * 64 + lane) << 3));
            acc = __builtin_amdgcn_mfma_f32_16x16x32_f16(a[ks], b, acc, 0, 0, 0);
        }
        int col = ct * 16 + m;
        int isL = (col < 300);
        int isR = (col >= 304 && col < 604);
        if (isL | isR) {
            float bv = isL ? bl[col] : br[col - 304];
            _Float16* tab = isL ? (xlh + col) : (xrh + (col - 304));
            #pragma unroll
            for (int reg = 0; reg < 4; ++reg) {
                int row = rbase + reg;
                if (row < n)
                    tab[(size_t)row * C_DIM] = (_Float16)(acc[reg] + bv);
            }
        }
    }
}

// ---------- gat_gather: chunked softmax (8 edges/iter), wide row loads ----------
// lane owns cols {4*lane..4*lane+3} (from first 512 B of row) and, for lane<22,
// tail cols {256+2*lane, 257+2*lane}. Per edge: 1 dwordx2 + 1 masked dword.
// leaky(z).att == dot(z,0.6att) + dot(|z|,0.4att)   (slope 0.2)
__global__ __launch_bounds__(256) void gat_gather(
    const int* __restrict__ csr_src, const unsigned* __restrict__ offs,
    const _Float16* __restrict__ xlh, const _Float16* __restrict__ xrh,
    const float* __restrict__ att, const float* __restrict__ bias,
    const float* __restrict__ lw, const float* __restrict__ lb,
    float* __restrict__ y, int n)
{
    __shared__ __align__(16) float lds[4 * 560];   // per wave: part[8][68]
    float* part = lds + (threadIdx.x >> 6) * 560;

    const int wid  = (blockIdx.x * blockDim.x + threadIdx.x) >> 6;
    const int lane = threadIdx.x & 63;
    if (wid >= n) return;

    const bool has2 = (lane < 22);                 // tail cols 256+2*lane < 300
    const int t8   = lane & 7;
    const int o    = lane >> 3;
    const int bmain = lane << 3;                   // byte offset of main dwordx2
    const int btail = 512 + (lane << 2);           // byte offset of tail dword

    // xr row: same layout
    const char* xrp = (const char*)(xrh + (size_t)wid * C_DIM);
    uint2 um = *(const uint2*)(xrp + bmain);
    h2 xm0 = as_h2(um.x), xm1 = as_h2(um.y);
    h2 xt = {(_Float16)0, (_Float16)0};
    if (has2) xt = as_h2(*(const unsigned*)(xrp + btail));

    // 0.6*att / 0.4*att in f16 pairs, per-lane channel mapping
    h2 a06[3], a04[3];
    {
        int c0 = 4 * lane;
        float ax = att[c0], ay = att[c0 + 1], az = att[c0 + 2], aw = att[c0 + 3];
        a06[0].x = (_Float16)(0.6f * ax); a06[0].y = (_Float16)(0.6f * ay);
        a04[0].x = (_Float16)(0.4f * ax); a04[0].y = (_Float16)(0.4f * ay);
        a06[1].x = (_Float16)(0.6f * az); a06[1].y = (_Float16)(0.6f * aw);
        a04[1].x = (_Float16)(0.4f * az); a04[1].y = (_Float16)(0.4f * aw);
        int ctl = 256 + 2 * lane;
        float tx = has2 ? att[ctl] : 0.f;
        float ty = has2 ? att[ctl + 1] : 0.f;
        a06[2].x = (_Float16)(0.6f * tx); a06[2].y = (_Float16)(0.6f * ty);
        a04[2].x = (_Float16)(0.4f * tx); a04[2].y = (_Float16)(0.4f * ty);
    }

    f32x2 acc2[3] = {{0.f, 0.f}, {0.f, 0.f}, {0.f, 0.f}};
    float den = 0.f;

    const unsigned start = offs[wid];
    const int totalE = (int)(offs[wid + 1] - start) + 1;   // + self loop (k==0)
    const char* basep = (const char*)xlh;

    for (int base = 0; base < totalE; base += CH) {
        int idv = wid;                                      // self-loop & filler
        {
            int k = base + lane;
            if (lane < CH && k > 0 && k < totalE) idv = csr_src[start + k - 1];
        }
        int rowb = idv * (C_DIM * 2);
        int ro[CH];
        #pragma unroll
        for (int tt = 0; tt < CH; ++tt) ro[tt] = __shfl(rowb, tt);

        uint2 pkm[CH]; unsigned pkt[CH];
        #pragma unroll
        for (int tt = 0; tt < CH; ++tt) {
            pkm[tt] = *(const uint2*)(basep + ro[tt] + bmain);
            pkt[tt] = 0u;
        }
        if (has2) {
            #pragma unroll
            for (int tt = 0; tt < CH; ++tt)
                pkt[tt] = *(const unsigned*)(basep + ro[tt] + btail);
        }

        // per-edge per-lane partial logits -> LDS (wave-local region)
        #pragma unroll
        for (int tt = 0; tt < CH; ++tt) {
            h2 z0 = as_h2(pkm[tt].x) + xm0;
            h2 z1 = as_h2(pkm[tt].y) + xm1;
            h2 z2 = as_h2(pkt[tt]) + xt;
            float p = fdot2w(z0, a06[0], 0.f);
            p = fdot2w(as_h2(as_u(z0) & 0x7FFF7FFFu), a04[0], p);
            p = fdot2w(z1, a06[1], p);
            p = fdot2w(as_h2(as_u(z1) & 0x7FFF7FFFu), a04[1], p);
            p = fdot2w(z2, a06[2], p);
            p = fdot2w(as_h2(as_u(z2) & 0x7FFF7FFFu), a04[2], p);
            part[tt * 68 + lane] = p;
        }

        // transpose-reduce: 8 lanes per edge-row, rotated b128 reads
        float wgt;
        {
            const int oo = (o + t8) & 7;
            const float* rp = part + t8 * 68 + oo * 8;
            float4 s0 = *(const float4*)(rp + 0);
            float4 s1 = *(const float4*)(rp + 4);
            float e = ((s0.x + s0.y) + (s0.z + s0.w)) + ((s1.x + s1.y) + (s1.z + s1.w));
            e += __shfl_xor(e, 8);
            e += __shfl_xor(e, 16);
            e += __shfl_xor(e, 32);
            bool valid = (base + t8) < totalE;
            wgt = valid ? __expf(fminf(e, 60.f)) : 0.f;
        }

        #pragma unroll
        for (int tt = 0; tt < CH; ++tt) {
            float wt = __shfl(wgt, tt);
            den += wt;
            f32x2 wt2 = {wt, wt};
            acc2[0] = fma2(wt2, upv(pkm[tt].x), acc2[0]);
            acc2[1] = fma2(wt2, upv(pkm[tt].y), acc2[1]);
            acc2[2] = fma2(wt2, upv(pkt[tt]), acc2[2]);
        }
    }

    // epilogue: normalize, +bias, relu, dot lw, sigmoid
    const float invd = 1.f / den;
    float dot = 0.f;
    {
        int c0 = 4 * lane;
        float h;
        h = fmaf(acc2[0].x, invd, bias[c0]);     h = h > 0.f ? h : 0.f; dot = fmaf(h, lw[c0], dot);
        h = fmaf(acc2[0].y, invd, bias[c0 + 1]); h = h > 0.f ? h : 0.f; dot = fmaf(h, lw[c0 + 1], dot);
        h = fmaf(acc2[1].x, invd, bias[c0 + 2]); h = h > 0.f ? h : 0.f; dot = fmaf(h, lw[c0 + 2], dot);
        h = fmaf(acc2[1].y, invd, bias[c0 + 3]); h = h > 0.f ? h : 0.f; dot = fmaf(h, lw[c0 + 3], dot);
        if (has2) {
            int ctl = 256 + 2 * lane;
            h = fmaf(acc2[2].x, invd, bias[ctl]);     h = h > 0.f ? h : 0.f; dot = fmaf(h, lw[ctl], dot);
            h = fmaf(acc2[2].y, invd, bias[ctl + 1]); h = h > 0.f ? h : 0.f; dot = fmaf(h, lw[ctl + 1], dot);
        }
    }
    #pragma unroll
    for (int off = 32; off; off >>= 1) dot += __shfl_xor(dot, off);
    if (lane == 0) y[wid] = 1.f / (1.f + __expf(-(dot + lb[0])));
}

extern "C" void kernel_launch(void* const* d_in, const int* in_sizes, int n_in,
                              void* d_out, int out_size, void* d_ws, size_t ws_size,
                              hipStream_t stream)
{
    const float* x    = (const float*)d_in[0];
    const int*   ei   = (const int*)d_in[1];
    const float* Wl   = (const float*)d_in[2];
    const float* bl   = (const float*)d_in[3];
    const float* Wr   = (const float*)d_in[4];
    const float* br   = (const float*)d_in[5];
    const float* att  = (const float*)d_in[6];
    const float* bias = (const float*)d_in[7];
    const float* lw   = (const float*)d_in[8];
    const float* lb   = (const float*)d_in[9];
    float* y = (float*)d_out;

    const int n  = in_sizes[0] / F_IN;   // 50000
    const int nE = in_sizes[1] / 2;      // 800000
    const int* src_arr = ei;
    const int* dst_arr = ei + nE;
    const int nblk  = (n + 1023) / 1024;   // 49 <= 64
    const int nhist = (nE + 255) / 256;    // 3125
    const int ngemm = (n + 63) / 64;       // 782

    // ws: xlh | xrh | Bp | counts | offs(n+1) | cursor | bsum(64) | csr_src
    _Float16* xlh     = (_Float16*)d_ws;
    _Float16* xrh     = xlh + (size_t)n * C_DIM;
    _Float16* Bp      = xrh + (size_t)n * C_DIM;
    unsigned* counts  = (unsigned*)(Bp + NCT * 4 * 64 * 8);
    unsigned* offs    = counts + n;
    unsigned* cursor  = offs + (n + 1);
    unsigned* bsum    = cursor + n;
    int*      csr_src = (int*)(bsum + 64);

    convert_w<<<(640 * F_IN + 255) / 256, 256, 0, stream>>>(Wl, Wr, Bp);
    hipMemsetAsync(counts, 0, (size_t)n * sizeof(unsigned), stream);
    hist_kernel<<<nhist, 256, 0, stream>>>(dst_arr, counts, nE);
    scan_part<<<nblk, 256, 0, stream>>>(counts, bsum, n);
    scan_mid<<<1, 64, 0, stream>>>(bsum, offs, nblk, n);
    scan_final<<<nblk, 256, 0, stream>>>(counts, bsum, offs, cursor, n);
    scatter_csr<<<nhist, 256, 0, stream>>>(src_arr, dst_arr, cursor, csr_src, nE);
    gemm_xlxr<<<ngemm, 256, 0, stream>>>(x, Bp, bl, br, xlh, xrh, n);
    gat_gather<<<(n + 3) / 4, 256, 0, stream>>>(csr_src, offs, xlh, xrh, att, bias, lw, lb, y, n);
}

// Round 12
// 315.478 us; speedup vs baseline: 1.0914x; 1.0163x over previous
//
#include <hip/hip_runtime.h>
#include <hip/hip_fp16.h>

#define F_IN 128
#define C_DIM 300
#define NEG_SLOPE 0.2f
#define NCT  40           // col-tile count for Bp (640 padded cols)
#define CH   8            // edges per chunk in gat_gather
#define NCONV 320         // convert_w blocks in prep

typedef _Float16 half8 __attribute__((ext_vector_type(8)));
typedef _Float16 half4 __attribute__((ext_vector_type(4)));
typedef _Float16 h2    __attribute__((ext_vector_type(2)));
typedef float    f32x4 __attribute__((ext_vector_type(4)));
typedef float    f32x2 __attribute__((ext_vector_type(2)));

__device__ inline h2 as_h2(unsigned u) { union { unsigned u; h2 h; } c; c.u = u; return c.h; }
__device__ inline unsigned as_u(h2 h)  { union { unsigned u; h2 h; } c; c.h = h; return c.u; }
__device__ inline f32x2 upv(unsigned u) {
    h2 h = as_h2(u);
    f32x2 r; r.x = (float)h.x; r.y = (float)h.y; return r;
}
__device__ inline f32x2 fma2(f32x2 a, f32x2 b, f32x2 c) {
#if __has_builtin(__builtin_elementwise_fma)
    return __builtin_elementwise_fma(a, b, c);
#else
    f32x2 r; r.x = fmaf(a.x, b.x, c.x); r.y = fmaf(a.y, b.y, c.y); return r;
#endif
}

#if __has_builtin(__builtin_amdgcn_fdot2)
__device__ inline float fdot2w(h2 a, h2 b, float c) {
    return __builtin_amdgcn_fdot2(a, b, c, false);
}
#else
__device__ inline float fdot2w(h2 a, h2 b, float c) {
    return fmaf((float)a.y, (float)b.y, fmaf((float)a.x, (float)b.x, c));
}
#endif

// ---------- prep: convert_w (blocks [0,NCONV)) + hist (rest); no LDS ----------
__global__ __launch_bounds__(256) void prep(
    const float* __restrict__ Wl, const float* __restrict__ Wr,
    _Float16* __restrict__ Bp, const int* __restrict__ dst,
    unsigned* __restrict__ counts, int nE)
{
    if ((int)blockIdx.x < NCONV) {
        int idx = blockIdx.x * 256 + threadIdx.x;        // 0 .. 640*128-1
        if (idx >= 640 * F_IN) return;
        int nn = idx % 640;                               // coalesced W reads
        int k  = idx / 640;
        float v = 0.f;
        if (nn < 300)                   v = Wl[k * C_DIM + nn];
        else if (nn >= 304 && nn < 604) v = Wr[k * C_DIM + (nn - 304)];
        int ct = nn >> 4, n16 = nn & 15;
        int kr = k & 31,  ks  = k >> 5;
        int lane = ((kr >> 3) << 4) | n16;
        int j = k & 7;
        Bp[((((ct * 4 + ks) * 64) + lane) << 3) | j] = (_Float16)v;
    } else {
        int j = (blockIdx.x - NCONV) * 256 + threadIdx.x;
        if (j < nE) atomicAdd(counts + dst[j], 1u);
    }
}

// ---- scan phase 1: per-block sums (1024 counts per block) ----
__global__ __launch_bounds__(256) void scan_part(
    const unsigned* __restrict__ counts, unsigned* __restrict__ bsum, int n)
{
    __shared__ unsigned s[256];
    const int t = threadIdx.x;
    const int base = blockIdx.x * 1024 + t * 4;
    unsigned v = 0;
    #pragma unroll
    for (int i = 0; i < 4; ++i) {
        int idx = base + i;
        if (idx < n) v += counts[idx];
    }
    s[t] = v;
    __syncthreads();
    for (int off = 128; off > 0; off >>= 1) {
        if (t < off) s[t] += s[t + off];
        __syncthreads();
    }
    if (t == 0) bsum[blockIdx.x] = s[0];
}

// ---- scan phase 2: each block scans all bsums itself (nblk<=64), then local scan ----
__global__ __launch_bounds__(256) void scan_final(
    const unsigned* __restrict__ counts, const unsigned* __restrict__ bsum,
    unsigned* __restrict__ offs, unsigned* __restrict__ cursor, int nblk, int n)
{
    __shared__ unsigned s[256];
    __shared__ unsigned sbase;
    const int t = threadIdx.x;

    if (t < 64) {
        unsigned v = (t < nblk) ? bsum[t] : 0u;
        unsigned inc = v;
        #pragma unroll
        for (int off = 1; off < 64; off <<= 1) {
            unsigned u = __shfl_up(inc, off);
            if (t >= off) inc += u;
        }
        if (t == (int)blockIdx.x) sbase = inc - v;       // exclusive prefix of this block
        if (blockIdx.x == 0 && t == 63) offs[n] = inc;   // grand total
    }

    const int base = blockIdx.x * 1024 + t * 4;
    unsigned c[4];
    unsigned v = 0;
    #pragma unroll
    for (int i = 0; i < 4; ++i) {
        int idx = base + i;
        c[i] = (idx < n) ? counts[idx] : 0u;
        v += c[i];
    }
    s[t] = v;
    __syncthreads();
    for (int off = 1; off < 256; off <<= 1) {
        unsigned u = (t >= off) ? s[t - off] : 0u;
        __syncthreads();
        if (t >= off) s[t] += u;
        __syncthreads();
    }
    unsigned run = sbase + s[t] - v;
    #pragma unroll
    for (int i = 0; i < 4; ++i) {
        int idx = base + i;
        if (idx < n) {
            offs[idx] = run;
            cursor[idx] = run;
            run += c[i];
        }
    }
}

// ---------- scatter_gemm: 64-row MFMA gemm (blocks [0,ngemm)) + CSR scatter (rest) ----------
// 17.4 KB LDS -> 9 blocks/CU by LDS >= 8-block wave cap: fusion costs zero occupancy.
__global__ __launch_bounds__(256) void scatter_gemm(
    const float* __restrict__ x, const _Float16* __restrict__ Bp,
    const float* __restrict__ bl, const float* __restrict__ br,
    _Float16* __restrict__ xlh, _Float16* __restrict__ xrh, int n,
    const int* __restrict__ src, const int* __restrict__ dst,
    unsigned* __restrict__ cursor, int* __restrict__ csr_src, int nE, int ngemm)
{
    __shared__ __align__(16) _Float16 xs[64][136];   // 17.4 KB
    if ((int)blockIdx.x >= ngemm) {
        int j = (blockIdx.x - ngemm) * 256 + threadIdx.x;
        if (j < nE) {
            unsigned p = atomicAdd(cursor + dst[j], 1u);
            csr_src[p] = src[j];
        }
        return;
    }

    const int rb0 = blockIdx.x * 64;
    const int t   = threadIdx.x;

    #pragma unroll
    for (int i = 0; i < 8; ++i) {
        int flat = (i * 256 + t) * 4;
        int r = flat >> 7;
        int k = flat & 127;
        int gr = rb0 + r;
        if (gr >= n) gr = n - 1;
        float4 v = *reinterpret_cast<const float4*>(x + (size_t)gr * F_IN + k);
        half4 h = { (_Float16)v.x, (_Float16)v.y, (_Float16)v.z, (_Float16)v.w };
        *reinterpret_cast<half4*>(&xs[r][k]) = h;
    }
    __syncthreads();

    const int w    = t >> 6;
    const int lane = t & 63;
    const int m    = lane & 15;
    const int quad = lane >> 4;

    // A-fragments for this wave's 16 rows, all 4 K-steps, kept in regs
    half8 a[4];
    #pragma unroll
    for (int ks = 0; ks < 4; ++ks)
        a[ks] = *reinterpret_cast<const half8*>(&xs[w * 16 + m][ks * 32 + quad * 8]);

    const int rbase = rb0 + w * 16 + quad * 4;

    #pragma unroll 4
    for (int ct = 0; ct < NCT; ++ct) {
        f32x4 acc = {0.f, 0.f, 0.f, 0.f};
        #pragma unroll
        for (int ks = 0; ks < 4; ++ks) {
            half8 b = *reinterpret_cast<const half8*>(
                Bp + (((size_t)(ct * 4 + ks) * 64 + lane) << 3));
            acc = __builtin_amdgcn_mfma_f32_16x16x32_f16(a[ks], b, acc, 0, 0, 0);
        }
        int col = ct * 16 + m;
        int isL = (col < 300);
        int isR = (col >= 304 && col < 604);
        if (isL | isR) {
            float bv = isL ? bl[col] : br[col - 304];
            _Float16* tab = isL ? (xlh + col) : (xrh + (col - 304));
            #pragma unroll
            for (int reg = 0; reg < 4; ++reg) {
                int row = rbase + reg;
                if (row < n)
                    tab[(size_t)row * C_DIM] = (_Float16)(acc[reg] + bv);
            }
        }
    }
}

// ---------- gat_gather: R7's proven version (chunked softmax, 8 edges/iter) ----------
// one wave per node; lane owns channels c = 128k + 2*lane + j
// leaky(z).att == dot(z,0.6att) + dot(|z|,0.4att)   (slope 0.2)
__global__ __launch_bounds__(256) void gat_gather(
    const int* __restrict__ csr_src, const unsigned* __restrict__ offs,
    const _Float16* __restrict__ xlh, const _Float16* __restrict__ xrh,
    const float* __restrict__ att, const float* __restrict__ bias,
    const float* __restrict__ lw, const float* __restrict__ lb,
    float* __restrict__ y, int n)
{
    __shared__ __align__(16) float lds[4 * 560];   // per wave: part[8][68]
    float* part = lds + (threadIdx.x >> 6) * 560;

    const int wid  = (blockIdx.x * blockDim.x + threadIdx.x) >> 6;
    const int lane = threadIdx.x & 63;
    if (wid >= n) return;

    const int l2   = 2 * lane;
    const bool has2 = (lane < 22);
    const int t8   = lane & 7;
    const int o    = lane >> 3;
    const int byteoff = lane * 4;

    const _Float16* xrrow = xrh + (size_t)wid * C_DIM;
    h2 xr0 = *(const h2*)(xrrow + l2);
    h2 xr1 = *(const h2*)(xrrow + 128 + l2);
    h2 xr2 = {(_Float16)0, (_Float16)0};
    if (has2) xr2 = *(const h2*)(xrrow + 256 + l2);

    h2 a06[3], a04[3];
    #pragma unroll
    for (int k = 0; k < 3; ++k) {
        int c = 128 * k + l2;
        float ax = (c < C_DIM) ? att[c] : 0.f;
        float ay = (c + 1 < C_DIM) ? att[c + 1] : 0.f;
        a06[k].x = (_Float16)(0.6f * ax); a06[k].y = (_Float16)(0.6f * ay);
        a04[k].x = (_Float16)(0.4f * ax); a04[k].y = (_Float16)(0.4f * ay);
    }

    f32x2 acc2[3] = {{0.f, 0.f}, {0.f, 0.f}, {0.f, 0.f}};
    float den = 0.f;

    const unsigned start = offs[wid];
    const int totalE = (int)(offs[wid + 1] - start) + 1;   // + self loop (k==0)
    const char* basep = (const char*)xlh;

    for (int base = 0; base < totalE; base += CH) {
        int idv = wid;                                      // self-loop & filler
        {
            int k = base + lane;
            if (lane < CH && k > 0 && k < totalE) idv = csr_src[start + k - 1];
        }
        int rowb = idv * (C_DIM * 2);
        int ro[CH];
        #pragma unroll
        for (int tt = 0; tt < CH; ++tt) ro[tt] = __shfl(rowb, tt);

        unsigned pk0[CH], pk1[CH], pk2[CH];
        #pragma unroll
        for (int tt = 0; tt < CH; ++tt) {
            const char* p = basep + ro[tt] + byteoff;
            pk0[tt] = *(const unsigned*)(p);
            pk1[tt] = *(const unsigned*)(p + 256);
            pk2[tt] = 0u;
        }
        if (has2) {
            #pragma unroll
            for (int tt = 0; tt < CH; ++tt)
                pk2[tt] = *(const unsigned*)(basep + ro[tt] + byteoff + 512);
        }

        #pragma unroll
        for (int tt = 0; tt < CH; ++tt) {
            h2 z0 = as_h2(pk0[tt]) + xr0;
            h2 z1 = as_h2(pk1[tt]) + xr1;
            h2 z2 = as_h2(pk2[tt]) + xr2;
            float p = fdot2w(z0, a06[0], 0.f);
            p = fdot2w(as_h2(as_u(z0) & 0x7FFF7FFFu), a04[0], p);
            p = fdot2w(z1, a06[1], p);
            p = fdot2w(as_h2(as_u(z1) & 0x7FFF7FFFu), a04[1], p);
            p = fdot2w(z2, a06[2], p);
            p = fdot2w(as_h2(as_u(z2) & 0x7FFF7FFFu), a04[2], p);
            part[tt * 68 + lane] = p;
        }

        float wgt;
        {
            const int oo = (o + t8) & 7;
            const float* rp = part + t8 * 68 + oo * 8;
            float4 s0 = *(const float4*)(rp + 0);
            float4 s1 = *(const float4*)(rp + 4);
            float e = ((s0.x + s0.y) + (s0.z + s0.w)) + ((s1.x + s1.y) + (s1.z + s1.w));
            e += __shfl_xor(e, 8);
            e += __shfl_xor(e, 16);
            e += __shfl_xor(e, 32);
            bool valid = (base + t8) < totalE;
            wgt = valid ? __expf(fminf(e, 60.f)) : 0.f;
        }

        #pragma unroll
        for (int tt = 0; tt < CH; ++tt) {
            float wt = __shfl(wgt, tt);
            den += wt;
            f32x2 wt2 = {wt, wt};
            acc2[0] = fma2(wt2, upv(pk0[tt]), acc2[0]);
            acc2[1] = fma2(wt2, upv(pk1[tt]), acc2[1]);
            acc2[2] = fma2(wt2, upv(pk2[tt]), acc2[2]);
        }
    }

    const float invd = 1.f / den;
    float dot = 0.f;
    #pragma unroll
    for (int k = 0; k < 3; ++k) {
        #pragma unroll
        for (int j = 0; j < 2; ++j) {
            int c = 128 * k + l2 + j;
            float b = (c < C_DIM) ? bias[c] : 0.f;
            float l = (c < C_DIM) ? lw[c] : 0.f;
            float a = (j == 0) ? acc2[k].x : acc2[k].y;
            float h = fmaf(a, invd, b);
            h = h > 0.f ? h : 0.f;
            dot = fmaf(h, l, dot);
        }
    }
    #pragma unroll
    for (int off = 32; off; off >>= 1) dot += __shfl_xor(dot, off);
    if (lane == 0) y[wid] = 1.f / (1.f + __expf(-(dot + lb[0])));
}

extern "C" void kernel_launch(void* const* d_in, const int* in_sizes, int n_in,
                              void* d_out, int out_size, void* d_ws, size_t ws_size,
                              hipStream_t stream)
{
    const float* x    = (const float*)d_in[0];
    const int*   ei   = (const int*)d_in[1];
    const float* Wl   = (const float*)d_in[2];
    const float* bl   = (const float*)d_in[3];
    const float* Wr   = (const float*)d_in[4];
    const float* br   = (const float*)d_in[5];
    const float* att  = (const float*)d_in[6];
    const float* bias = (const float*)d_in[7];
    const float* lw   = (const float*)d_in[8];
    const float* lb   = (const float*)d_in[9];
    float* y = (float*)d_out;

    const int n  = in_sizes[0] / F_IN;   // 50000
    const int nE = in_sizes[1] / 2;      // 800000
    const int* src_arr = ei;
    const int* dst_arr = ei + nE;
    const int nblk  = (n + 1023) / 1024;   // 49 <= 64
    const int nhist = (nE + 255) / 256;    // 3125
    const int ngemm = (n + 63) / 64;       // 782

    // ws: xlh | xrh | Bp | counts | offs(n+1) | cursor | bsum(64) | csr_src
    _Float16* xlh     = (_Float16*)d_ws;
    _Float16* xrh     = xlh + (size_t)n * C_DIM;
    _Float16* Bp      = xrh + (size_t)n * C_DIM;
    unsigned* counts  = (unsigned*)(Bp + NCT * 4 * 64 * 8);
    unsigned* offs    = counts + n;
    unsigned* cursor  = offs + (n + 1);
    unsigned* bsum    = cursor + n;
    int*      csr_src = (int*)(bsum + 64);

    hipMemsetAsync(counts, 0, (size_t)n * sizeof(unsigned), stream);
    prep<<<NCONV + nhist, 256, 0, stream>>>(Wl, Wr, Bp, dst_arr, counts, nE);
    scan_part<<<nblk, 256, 0, stream>>>(counts, bsum, n);
    scan_final<<<nblk, 256, 0, stream>>>(counts, bsum, offs, cursor, nblk, n);
    scatter_gemm<<<ngemm + nhist, 256, 0, stream>>>(
        x, Bp, bl, br, xlh, xrh, n, src_arr, dst_arr, cursor, csr_src, nE, ngemm);
    gat_gather<<<(n + 3) / 4, 256, 0, stream>>>(csr_src, offs, xlh, xrh, att, bias, lw, lb, y, n);
}